// Round 1
// baseline (132.044 us; speedup 1.0000x reference)
//
#include <hip/hip_runtime.h>

// Reference: y = convT3d(x, sum_o(weight), stride=2, pad=2, k=5) + sum(bias)
//            out = maxpool3(maxpool2(y))  == 6x6x6 stride-6 max over y
// x: (16,32,16,32,32) f32 ; weight: (32,64,5,5,5) ; bias: (64,)
// y: (16,1,31,63,63) ; out: (16,1,5,10,10) = 8000 f32
//
// Per-dim transposed-conv taps: y[o] = sum_id x[id] * w[o+2-2*id], with
// (o+2-2*id) in [0,4]. Even o -> 3 taps, odd o -> 2 taps.
//
// ws layout (floats): wpad[32][8][8][8] zero-padded kernel (idx 0..16383),
//                     bias_sum at idx 16384.

#define DIN 16
#define HIN 32
#define WIN 32
#define CH_STRIDE (DIN*HIN*WIN)   // 16384
#define N_STRIDE  (32*CH_STRIDE)  // 524288

__global__ __launch_bounds__(256) void prep_kernel(const float* __restrict__ w,
                                                   const float* __restrict__ bias,
                                                   float* __restrict__ ws) {
  int i = blockIdx.x;   // input channel 0..31
  int t = threadIdx.x;
  for (int s = t; s < 512; s += 256) {
    int kw = s & 7, kh = (s >> 3) & 7, kd = s >> 6;
    float v = 0.f;
    if (kd < 5 && kh < 5 && kw < 5) {
      const float* wp = w + (size_t)i * 64 * 125 + kd * 25 + kh * 5 + kw;
      #pragma unroll 8
      for (int o = 0; o < 64; ++o) v += wp[o * 125];
    }
    ws[i * 512 + s] = v;
  }
  if (i == 0 && t == 0) {
    float b = 0.f;
    for (int o = 0; o < 64; ++o) b += bias[o];
    ws[16384] = b;
  }
}

// Block: (n, dc 0..4, hq 0..1, wc2 0..4) -> y tile od=6dc+td(0..5),
// oh=30hq+ohl(0..29), ow=12*wc2+owl(0..11). 180 compute threads (td,ohl),
// each owns a 12-wide ow row. Channels staged 4 at a time (8 phases).
__global__ __launch_bounds__(192) void conv_pool_kernel(const float* __restrict__ x,
                                                        const float* __restrict__ ws,
                                                        float* __restrict__ out) {
  // xs: [ic4][ad5][bh17 rows of stride 12] ; plane stride 204, ch stride 1020
  __shared__ __align__(16) float xs[4080];
  // wl: [ic4][kd8*100 + kh8*12 + kw] ; ch stride 800 (only kw 0..4 read)
  __shared__ __align__(16) float wl[3200];
  __shared__ float red[360];

  int b   = blockIdx.x;
  int wc2 = b % 5;
  int hq  = (b / 5) % 2;
  int dc  = (b / 10) % 5;
  int n   = b / 50;

  int t   = threadIdx.x;
  int td  = t / 30;       // 0..5 for t<180
  int ohl = t % 30;       // 0..29
  int a0  = (td + 1) >> 1;
  int b0  = (ohl + 1) >> 1;

  const float* xn = x + (size_t)n * N_STRIDE;

  int id_base = 3 * dc - 1;
  int ih_base = 15 * hq - 1;
  int iw_base = 6 * wc2 - 1;

  float acc0=0,acc1=0,acc2=0,acc3=0,acc4=0,acc5=0,
        acc6=0,acc7=0,acc8=0,acc9=0,acc10=0,acc11=0;

  for (int p = 0; p < 8; ++p) {
    // ---- stage x chunk (channels 4p..4p+3): 4*5*17*8 = 2720 slots
    for (int s = t; s < 2720; s += 192) {
      int c  = s & 7;
      int r  = s >> 3;
      int bh = r % 17;
      int r2 = r / 17;
      int ad = r2 % 5;
      int ic = r2 / 5;
      int id = id_base + ad;
      int ih = ih_base + bh;
      int iw = iw_base + c;
      float v = 0.f;
      if ((id | ih | iw) >= 0)  // uppers are provably in range
        v = xn[(size_t)(p * 4 + ic) * CH_STRIDE + id * (HIN*WIN) + ih * WIN + iw];
      xs[(ic * 5 + ad) * 204 + bh * 12 + c] = v;
    }
    // ---- stage w chunk: 4*512 slots (zero-padded rows included)
    for (int s = t; s < 2048; s += 192) {
      int kw = s & 7, kh = (s >> 3) & 7, kd = (s >> 6) & 7, ic = s >> 9;
      wl[ic * 800 + kd * 100 + kh * 12 + kw] = ws[(p * 4 + ic) * 512 + (s & 511)];
    }
    __syncthreads();

    if (t < 180) {
      for (int ic = 0; ic < 4; ++ic) {
        const float* xc = &xs[ic * 1020];
        const float* wc = &wl[ic * 800];
        #pragma unroll
        for (int jd = 0; jd < 3; ++jd) {
          int ad = a0 + jd;
          int kd = (td + 4 - 2 * ad) & 7;   // pad taps -> rows 5..7 (zeros)
          if (ad > 4) ad = 4;               // clamped read is multiplied by 0
          #pragma unroll
          for (int jh = 0; jh < 3; ++jh) {
            int bh = b0 + jh;
            int kh = (ohl + 4 - 2 * bh) & 7;
            if (bh > 16) bh = 16;
            const float* xr = xc + ad * 204 + bh * 12;
            const float* wr = wc + kd * 100 + kh * 12;
            float4 xlo = *(const float4*)(xr);
            float4 xhi = *(const float4*)(xr + 4);
            float4 wv  = *(const float4*)(wr);
            float  w4  = wr[4];
            float x0=xlo.x, x1=xlo.y, x2=xlo.z, x3=xlo.w;
            float x4=xhi.x, x5=xhi.y, x6=xhi.z, x7=xhi.w;
            float w0=wv.x, w1=wv.y, w2=wv.z, w3=wv.w;
            // owl even: 3 taps (kw 4,2,0) ; odd: 2 taps (kw 3,1)
            acc0  += x0*w4; acc0  += x1*w2; acc0  += x2*w0;
            acc1  += x1*w3; acc1  += x2*w1;
            acc2  += x1*w4; acc2  += x2*w2; acc2  += x3*w0;
            acc3  += x2*w3; acc3  += x3*w1;
            acc4  += x2*w4; acc4  += x3*w2; acc4  += x4*w0;
            acc5  += x3*w3; acc5  += x4*w1;
            acc6  += x3*w4; acc6  += x4*w2; acc6  += x5*w0;
            acc7  += x4*w3; acc7  += x5*w1;
            acc8  += x4*w4; acc8  += x5*w2; acc8  += x6*w0;
            acc9  += x5*w3; acc9  += x6*w1;
            acc10 += x5*w4; acc10 += x6*w2; acc10 += x7*w0;
            acc11 += x6*w3; acc11 += x7*w1;
          }
        }
      }
    }
    __syncthreads();
  }

  // ---- fused 6x6x6 max-pool
  if (t < 180) {
    float g0 = fmaxf(fmaxf(fmaxf(acc0,acc1),fmaxf(acc2,acc3)),fmaxf(acc4,acc5));
    float g1 = fmaxf(fmaxf(fmaxf(acc6,acc7),fmaxf(acc8,acc9)),fmaxf(acc10,acc11));
    red[t * 2]     = g0;
    red[t * 2 + 1] = g1;
  }
  __syncthreads();
  if (t < 10) {
    int hs   = t >> 1;   // 0..4
    int wsub = t & 1;    // 0..1
    float m = -3.4e38f;
    for (int tdd = 0; tdd < 6; ++tdd)
      for (int j = 0; j < 6; ++j) {
        int tt = tdd * 30 + hs * 6 + j;
        m = fmaxf(m, red[tt * 2 + wsub]);
      }
    m += ws[16384];
    int h = 5 * hq + hs;
    int w = 2 * wc2 + wsub;
    out[((n * 5 + dc) * 10 + h) * 10 + w] = m;
  }
}

extern "C" void kernel_launch(void* const* d_in, const int* in_sizes, int n_in,
                              void* d_out, int out_size, void* d_ws, size_t ws_size,
                              hipStream_t stream) {
  const float* x    = (const float*)d_in[0];
  const float* w    = (const float*)d_in[1];
  const float* bias = (const float*)d_in[2];
  float* outp = (float*)d_out;
  float* ws   = (float*)d_ws;
  prep_kernel<<<32, 256, 0, stream>>>(w, bias, ws);
  conv_pool_kernel<<<800, 192, 0, stream>>>(x, ws, outp);
}

// Round 2
// 111.044 us; speedup vs baseline: 1.1891x; 1.1891x over previous
//
#include <hip/hip_runtime.h>

// y = convT3d(x, weight.sum(oc), stride=2, pad=2, k=5) + sum(bias); out = 6x6x6/6 max.
// Tap algebra (verified R1): y[o] = sum_id x[id]*w[k], k = o+2-2*id in [0,4].
// Even o: k in {0,2,4} (3 taps); odd o: k in {1,3} (2 taps). Only y[0:30,0:60,0:60] feeds pooling.
// Stage1: per thread 2od x 2oh x 12ow partials (48 acc), 9 shared x-rows/ch, exact 25 tap-pairs.
// Stage2: sum channel-chunk partials + 6^3 max + bias.

#define DIN 16
#define HIN 32
#define WIN 32
#define CHSTR (DIN*HIN*WIN)      // 16384
#define NSTRIDE (32*CHSTR)
#define Y_N 108000               // 30*60*60
#define Y_TOT (16*Y_N)           // 1728000 floats per chunk region

// ---------------- stage 1: conv partials -------------------------------
template<int NCHUNK>
__global__ __launch_bounds__(256) void conv_stage1(const float* __restrict__ x,
                                                   const float* __restrict__ ws,
                                                   float* __restrict__ part, int woff) {
  constexpr int ICPB = 32 / NCHUNK;
  // xs: 2 ch x 5 planes x 17 rows x stride 44 (cols 0..3 zero, 4..35 = iw 0..31)
  __shared__ __align__(16) float xs[2 * 5 * 17 * 44];

  int blk   = blockIdx.x;
  int chunk = blk % NCHUNK;
  int hq    = (blk / NCHUNK) % 2;
  int dc    = (blk / (NCHUNK * 2)) % 5;
  int n     = blk / (NCHUNK * 10);
  int t     = threadIdx.x;

  // zero left-halo cols (col 3 == iw=-1; cols 0..2 unread) once; persists across phases
  for (int r = t; r < 170; r += 256) {
    float4 z = {0.f, 0.f, 0.f, 0.f};
    *(float4*)&xs[r * 44] = z;
  }

  int g = t % 5, q = t / 5, lmh = q % 15, lmd = q / 15;   // valid for t<225
  int id_base = 3 * dc - 1, ih_base = 15 * hq - 1;
  const float* xn    = x + (size_t)n * NSTRIDE + (size_t)(chunk * ICPB) * CHSTR;
  const float* wbase = ws + woff + (size_t)(chunk * ICPB) * 128;

  float acc[2][2][12] = {};

  for (int phs = 0; phs < ICPB / 2; ++phs) {
    // ---- stage 2 channels: 2*5*17 rows x 8 float4
    for (int s = t; s < 1360; s += 256) {
      int c4  = s & 7;
      int row = s >> 3;          // 0..169
      int bh  = row % 17;
      int pr  = row / 17;        // lic*5+ad
      int ad  = pr % 5, lic = pr / 5;
      int id = id_base + ad, ih = ih_base + bh;
      float4 v = {0.f, 0.f, 0.f, 0.f};
      if ((id | ih) >= 0)        // upper bounds provably in range
        v = *(const float4*)&xn[(size_t)(phs * 2 + lic) * CHSTR + (id * HIN + ih) * WIN + c4 * 4];
      *(float4*)&xs[row * 44 + 4 + c4 * 4] = v;
    }
    __syncthreads();

    if (t < 225) {
      constexpr int KD[3][2] = {{4, -1}, {2, 3}, {0, 1}};  // (tap kd per plane-offset a; pd==dt)
      for (int lic = 0; lic < 2; ++lic) {
        const float* wc = wbase + (size_t)(phs * 2 + lic) * 128;
        const float* xc = &xs[lic * 5 * 17 * 44];
#pragma unroll
        for (int a = 0; a < 3; ++a) {
#pragma unroll
          for (int b = 0; b < 3; ++b) {
            const float* xr = xc + ((lmd + a) * 17 + (lmh + b)) * 44 + 6 * g + 3;
            float xv[8];
#pragma unroll
            for (int j = 0; j < 8; ++j) xv[j] = xr[j];
#pragma unroll
            for (int dt = 0; dt < 2; ++dt) {
              if (KD[a][dt] < 0) continue;
#pragma unroll
              for (int ht = 0; ht < 2; ++ht) {
                if (KD[b][ht] < 0) continue;
                const float* wr = wc + (KD[a][dt] * 5 + KD[b][ht]) * 5;
                float w0 = wr[0], w1 = wr[1], w2 = wr[2], w3 = wr[3], w4 = wr[4];
                float* A = acc[dt][ht];
#pragma unroll
                for (int v = 0; v < 6; ++v) {
                  A[2 * v]     += xv[v + 2] * w0;
                  A[2 * v]     += xv[v + 1] * w2;
                  A[2 * v]     += xv[v]     * w4;
                  A[2 * v + 1] += xv[v + 2] * w1;
                  A[2 * v + 1] += xv[v + 1] * w3;
                }
              }
            }
          }
        }
      }
    }
    __syncthreads();
  }

  if (t < 225) {
    float* pb = part + (size_t)chunk * Y_TOT + (size_t)n * Y_N;
    int md = 3 * dc + lmd, mh = 15 * hq + lmh;
#pragma unroll
    for (int pd = 0; pd < 2; ++pd)
#pragma unroll
      for (int ph = 0; ph < 2; ++ph) {
        int od = 2 * md + pd, oh = 2 * mh + ph;
        float* o = pb + (od * 60 + oh) * 60 + 12 * g;
#pragma unroll
        for (int u = 0; u < 12; u += 4) {
          float4 v = make_float4(acc[pd][ph][u], acc[pd][ph][u + 1],
                                 acc[pd][ph][u + 2], acc[pd][ph][u + 3]);
          *(float4*)&o[u] = v;
        }
      }
  }
}

// ---------------- stage 2: chunk-sum + 6^3 max + bias ------------------
template<int NCHUNK>
__global__ __launch_bounds__(256) void pool_stage2(const float* __restrict__ part,
                                                   const float* __restrict__ ws,
                                                   float* __restrict__ out, int woff) {
  __shared__ __align__(16) float buf[21600];
  __shared__ float red[200];
  int blk = blockIdx.x;           // n*5 + dc
  int dc = blk % 5, n = blk / 5;
  int t = threadIdx.x;
  const float* pb = part + (size_t)n * Y_N + dc * 21600;
  for (int s = t; s < 5400; s += 256) {
    float4 v = *(const float4*)&pb[4 * s];
#pragma unroll
    for (int c = 1; c < NCHUNK; ++c) {
      float4 w = *(const float4*)&pb[(size_t)c * Y_TOT + 4 * s];
      v.x += w.x; v.y += w.y; v.z += w.z; v.w += w.w;
    }
    *(float4*)&buf[4 * s] = v;
  }
  __syncthreads();
  if (t < 200) {
    int wc = t % 10, hc = (t / 10) % 10, p = t / 100;
    float m = -3.4e38f;
    for (int od = 0; od < 6; ++od)
      for (int j = 0; j < 6; ++j)
#pragma unroll
        for (int k = 0; k < 3; ++k)
          m = fmaxf(m, buf[(od * 60 + 6 * hc + j) * 60 + 6 * wc + 3 * p + k]);
    red[t] = m;
  }
  __syncthreads();
  if (t < 100) out[blk * 100 + t] = fmaxf(red[t], red[t + 100]) + ws[woff + 4096];
}

// ---------------- prep: weight oc-sum + bias sum -----------------------
__global__ __launch_bounds__(128) void prep2(const float* __restrict__ w,
                                             const float* __restrict__ bias,
                                             float* __restrict__ ws, int woff) {
  int i = blockIdx.x, t = threadIdx.x;
  if (t < 125) {
    const float* wp = w + (size_t)i * 64 * 125 + t;
    float v = 0.f;
#pragma unroll 8
    for (int o = 0; o < 64; ++o) v += wp[o * 125];
    ws[woff + i * 128 + t] = v;
  }
  if (i == 0 && t == 126) {
    float b = 0.f;
    for (int o = 0; o < 64; ++o) b += bias[o];
    ws[woff + 4096] = b;
  }
}

// ================= fallback (round-1 kernels, need only 64 KB ws) =======
__global__ __launch_bounds__(256) void prep_kernel(const float* __restrict__ w,
                                                   const float* __restrict__ bias,
                                                   float* __restrict__ ws) {
  int i = blockIdx.x;
  int t = threadIdx.x;
  for (int s = t; s < 512; s += 256) {
    int kw = s & 7, kh = (s >> 3) & 7, kd = s >> 6;
    float v = 0.f;
    if (kd < 5 && kh < 5 && kw < 5) {
      const float* wp = w + (size_t)i * 64 * 125 + kd * 25 + kh * 5 + kw;
#pragma unroll 8
      for (int o = 0; o < 64; ++o) v += wp[o * 125];
    }
    ws[i * 512 + s] = v;
  }
  if (i == 0 && t == 0) {
    float b = 0.f;
    for (int o = 0; o < 64; ++o) b += bias[o];
    ws[16384] = b;
  }
}

__global__ __launch_bounds__(192) void conv_pool_kernel(const float* __restrict__ x,
                                                        const float* __restrict__ ws,
                                                        float* __restrict__ out) {
  __shared__ __align__(16) float xs[4080];
  __shared__ __align__(16) float wl[3200];
  __shared__ float red[360];
  int b = blockIdx.x;
  int wc2 = b % 5, hq = (b / 5) % 2, dc = (b / 10) % 5, n = b / 50;
  int t = threadIdx.x;
  int td = t / 30, ohl = t % 30;
  int a0 = (td + 1) >> 1, b0 = (ohl + 1) >> 1;
  const float* xn = x + (size_t)n * NSTRIDE;
  int id_base = 3 * dc - 1, ih_base = 15 * hq - 1, iw_base = 6 * wc2 - 1;
  float acc0=0,acc1=0,acc2=0,acc3=0,acc4=0,acc5=0,acc6=0,acc7=0,acc8=0,acc9=0,acc10=0,acc11=0;
  for (int p = 0; p < 8; ++p) {
    for (int s = t; s < 2720; s += 192) {
      int c = s & 7; int r = s >> 3; int bh = r % 17; int r2 = r / 17;
      int ad = r2 % 5; int ic = r2 / 5;
      int id = id_base + ad, ih = ih_base + bh, iw = iw_base + c;
      float v = 0.f;
      if ((id | ih | iw) >= 0)
        v = xn[(size_t)(p * 4 + ic) * CHSTR + id * (HIN * WIN) + ih * WIN + iw];
      xs[(ic * 5 + ad) * 204 + bh * 12 + c] = v;
    }
    for (int s = t; s < 2048; s += 192) {
      int kw = s & 7, kh = (s >> 3) & 7, kd = (s >> 6) & 7, ic = s >> 9;
      wl[ic * 800 + kd * 100 + kh * 12 + kw] = ws[(p * 4 + ic) * 512 + (s & 511)];
    }
    __syncthreads();
    if (t < 180) {
      for (int ic = 0; ic < 4; ++ic) {
        const float* xc = &xs[ic * 1020];
        const float* wcc = &wl[ic * 800];
#pragma unroll
        for (int jd = 0; jd < 3; ++jd) {
          int ad = a0 + jd;
          int kd = (td + 4 - 2 * ad) & 7;
          if (ad > 4) ad = 4;
#pragma unroll
          for (int jh = 0; jh < 3; ++jh) {
            int bh = b0 + jh;
            int kh = (ohl + 4 - 2 * bh) & 7;
            if (bh > 16) bh = 16;
            const float* xr = xc + ad * 204 + bh * 12;
            const float* wr = wcc + kd * 100 + kh * 12;
            float4 xlo = *(const float4*)(xr);
            float4 xhi = *(const float4*)(xr + 4);
            float4 wv = *(const float4*)(wr);
            float w4 = wr[4];
            float x0=xlo.x,x1=xlo.y,x2=xlo.z,x3=xlo.w,x4=xhi.x,x5=xhi.y,x6=xhi.z,x7=xhi.w;
            float w0=wv.x,w1=wv.y,w2=wv.z,w3=wv.w;
            acc0+=x0*w4; acc0+=x1*w2; acc0+=x2*w0; acc1+=x1*w3; acc1+=x2*w1;
            acc2+=x1*w4; acc2+=x2*w2; acc2+=x3*w0; acc3+=x2*w3; acc3+=x3*w1;
            acc4+=x2*w4; acc4+=x3*w2; acc4+=x4*w0; acc5+=x3*w3; acc5+=x4*w1;
            acc6+=x3*w4; acc6+=x4*w2; acc6+=x5*w0; acc7+=x4*w3; acc7+=x5*w1;
            acc8+=x4*w4; acc8+=x5*w2; acc8+=x6*w0; acc9+=x5*w3; acc9+=x6*w1;
            acc10+=x5*w4; acc10+=x6*w2; acc10+=x7*w0; acc11+=x6*w3; acc11+=x7*w1;
          }
        }
      }
    }
    __syncthreads();
  }
  if (t < 180) {
    float g0 = fmaxf(fmaxf(fmaxf(acc0,acc1),fmaxf(acc2,acc3)),fmaxf(acc4,acc5));
    float g1 = fmaxf(fmaxf(fmaxf(acc6,acc7),fmaxf(acc8,acc9)),fmaxf(acc10,acc11));
    red[t * 2] = g0; red[t * 2 + 1] = g1;
  }
  __syncthreads();
  if (t < 10) {
    int hs = t >> 1, wsub = t & 1;
    float m = -3.4e38f;
    for (int tdd = 0; tdd < 6; ++tdd)
      for (int j = 0; j < 6; ++j) m = fmaxf(m, red[(tdd * 30 + hs * 6 + j) * 2 + wsub]);
    m += ws[16384];
    out[((n * 5 + dc) * 10 + (5 * hq + hs)) * 10 + (2 * wc2 + wsub)] = m;
  }
}

// ---------------- launch ----------------------------------------------
extern "C" void kernel_launch(void* const* d_in, const int* in_sizes, int n_in,
                              void* d_out, int out_size, void* d_ws, size_t ws_size,
                              hipStream_t stream) {
  const float* x    = (const float*)d_in[0];
  const float* w    = (const float*)d_in[1];
  const float* bias = (const float*)d_in[2];
  float* outp = (float*)d_out;
  float* ws   = (float*)d_ws;

  const size_t need4 = ((size_t)4 * Y_TOT + 4097) * 4;
  const size_t need2 = ((size_t)2 * Y_TOT + 4097) * 4;
  const size_t need1 = ((size_t)1 * Y_TOT + 4097) * 4;

  if (ws_size >= need4) {
    int woff = 4 * Y_TOT;
    prep2<<<32, 128, 0, stream>>>(w, bias, ws, woff);
    conv_stage1<4><<<160 * 4, 256, 0, stream>>>(x, ws, ws, woff);
    pool_stage2<4><<<80, 256, 0, stream>>>(ws, ws, outp, woff);
  } else if (ws_size >= need2) {
    int woff = 2 * Y_TOT;
    prep2<<<32, 128, 0, stream>>>(w, bias, ws, woff);
    conv_stage1<2><<<160 * 2, 256, 0, stream>>>(x, ws, ws, woff);
    pool_stage2<2><<<80, 256, 0, stream>>>(ws, ws, outp, woff);
  } else if (ws_size >= need1) {
    int woff = 1 * Y_TOT;
    prep2<<<32, 128, 0, stream>>>(w, bias, ws, woff);
    conv_stage1<1><<<160 * 1, 256, 0, stream>>>(x, ws, ws, woff);
    pool_stage2<1><<<80, 256, 0, stream>>>(ws, ws, outp, woff);
  } else {
    prep_kernel<<<32, 256, 0, stream>>>(w, bias, ws);
    conv_pool_kernel<<<800, 192, 0, stream>>>(x, ws, outp);
  }
}

// Round 3
// 97.055 us; speedup vs baseline: 1.3605x; 1.1441x over previous
//
#include <hip/hip_runtime.h>

// y = convT3d(x, weight.sum(oc), stride=2, pad=2, k=5) + sum(bias); out = 6^3 stride-6 max.
// Tap algebra (verified R1/R2): y[o] = sum_id x[id]*w[k], k = o+2-2*id in [0,4].
// Only y[0:30, 0:60, 0:60] feeds pooling.
// Stage1 tile: 6od x 30oh x 30ow per (n, dc, hq, wq, chunk). 225 threads (mw 15 x lmh 15),
// each owns acc[3 md][2 dt][2 ht][2 wt] = 24 outputs. x rows staged in LDS (17 cols + halo,
// stride 24); weights read wave-uniform from global (s_load). Exact 75 (m,kd,kh) taps x 5 FMA.

#define DIN 16
#define HIN 32
#define WIN 32
#define CHSTR (DIN*HIN*WIN)      // 16384
#define NSTRIDE (32*CHSTR)
#define Y_N 108000               // 30*60*60
#define Y_TOT (16*Y_N)
#define XSTR 24                  // LDS row stride (floats); 20 cols used

// ---- tap macro: acc[m][dt][ht][wt] over w taps; x0,x1,x2 = cols cb..cb+2 ----
#define TAP(m,dt,kd,ht,kh) { const float* wr = wc + ((kd)*5+(kh))*5; \
  acc[m][dt][ht][0] += x0*wr[4]; acc[m][dt][ht][0] += x1*wr[2]; acc[m][dt][ht][0] += x2*wr[0]; \
  acc[m][dt][ht][1] += x1*wr[3]; acc[m][dt][ht][1] += x2*wr[1]; }

#define DT0(HT,KH) TAP(0,0,4,HT,KH)
#define DT1(HT,KH) TAP(1,0,4,HT,KH) TAP(0,0,2,HT,KH) TAP(0,1,3,HT,KH)
#define DT2(HT,KH) TAP(2,0,4,HT,KH) TAP(1,0,2,HT,KH) TAP(1,1,3,HT,KH) TAP(0,0,0,HT,KH) TAP(0,1,1,HT,KH)
#define DT3(HT,KH) TAP(2,0,2,HT,KH) TAP(2,1,3,HT,KH) TAP(1,0,0,HT,KH) TAP(1,1,1,HT,KH)
#define DT4(HT,KH) TAP(2,0,0,HT,KH) TAP(2,1,1,HT,KH)

#define ROWB(AD,DB,TAPS) { const float* xr = xb + (AD)*(17*XSTR) + (DB)*XSTR; \
  float x0 = xr[0], x1 = xr[1], x2 = xr[2]; TAPS }

#define ADROWS(AD,DTX) \
  ROWB(AD,0, DTX(0,4)) \
  ROWB(AD,1, DTX(0,2) DTX(1,3)) \
  ROWB(AD,2, DTX(0,0) DTX(1,1))

template<int NCHUNK>
__global__ __launch_bounds__(256, 4) void conv_stage1(const float* __restrict__ x,
                                                      const float* __restrict__ ws,
                                                      float* part, int woff) {
  constexpr int ICPB  = 32 / NCHUNK;
  constexpr int NPHS  = ICPB / 2;
  __shared__ __align__(16) float xs[170 * XSTR];   // 2ch x 5 planes x 17 rows

  int blk = blockIdx.x;
  int s0  = blk % 320;
  int chunk = blk / 320;
  int wq = s0 % 2;
  int hq = (s0 / 2) % 2;
  int dc = (s0 / 4) % 5;
  int n  = s0 / 20;
  int t  = threadIdx.x;

  int mw  = t % 15;
  int lmh = t / 15;          // valid for t<225

  int id_base = 3 * dc - 1;
  int ih_base = 15 * hq - 1;
  int iwb     = wq ? 12 : -4;          // col c <-> iw = iwb + c
  int cb      = mw + (wq ? 2 : 3);     // read base col

  const float* xn  = x + (size_t)n * NSTRIDE + (size_t)(chunk * ICPB) * CHSTR;
  const float* wsw = ws + woff + (size_t)(chunk * ICPB) * 128;

  float acc[3][2][2][2] = {{{{0.f}}}};
  const float* xbase = &xs[lmh * XSTR + cb];

  for (int phs = 0; phs < NPHS; ++phs) {
    // ---- stage 2 channels: 170 rows x 10 float2 (cols 0..19; halo cols -> 0)
    for (int s = t; s < 1700; s += 256) {
      int c2  = s % 10;
      int row = s / 10;          // 0..169
      int bh  = row % 17;
      int q   = row / 17;
      int ad  = q % 5, lic = q / 5;
      int id = id_base + ad;
      int ih = ih_base + bh;
      int iw = iwb + 2 * c2;
      float2 v = make_float2(0.f, 0.f);
      if ((id | ih | iw) >= 0)   // uppers provably in range
        v = *(const float2*)&xn[(size_t)(phs * 2 + lic) * CHSTR + (id * HIN + ih) * WIN + iw];
      *(float2*)&xs[row * XSTR + 2 * c2] = v;
    }
    __syncthreads();

    if (t < 225) {
      {
        const float* wc = wsw + (size_t)(phs * 2) * 128;
        const float* xb = xbase;
        ADROWS(0,DT0) ADROWS(1,DT1) ADROWS(2,DT2) ADROWS(3,DT3) ADROWS(4,DT4)
      }
      {
        const float* wc = wsw + (size_t)(phs * 2 + 1) * 128;
        const float* xb = xbase + 85 * XSTR;
        ADROWS(0,DT0) ADROWS(1,DT1) ADROWS(2,DT2) ADROWS(3,DT3) ADROWS(4,DT4)
      }
    }
    __syncthreads();
  }

  if (t < 225) {
    float* pb = part + (size_t)chunk * Y_TOT + (size_t)n * Y_N;
#pragma unroll
    for (int m = 0; m < 3; ++m)
#pragma unroll
      for (int dt = 0; dt < 2; ++dt)
#pragma unroll
        for (int ht = 0; ht < 2; ++ht) {
          int od_g = 6 * dc + 2 * m + dt;
          int oh_g = 30 * hq + 2 * lmh + ht;
          int ow_g = 30 * wq + 2 * mw;
          *(float2*)&pb[(od_g * 60 + oh_g) * 60 + ow_g] =
              make_float2(acc[m][dt][ht][0], acc[m][dt][ht][1]);
        }
  }
}

// ---------------- stage 2: chunk-sum + 6^3 max + bias ------------------
template<int NCHUNK>
__global__ __launch_bounds__(256) void pool_stage2(const float* __restrict__ part,
                                                   const float* __restrict__ ws,
                                                   float* __restrict__ out, int woff) {
  __shared__ __align__(16) float buf[21600];
  __shared__ float red[200];
  int blk = blockIdx.x;           // n*5 + dc
  int dc = blk % 5, n = blk / 5;
  int t = threadIdx.x;
  const float* pb = part + (size_t)n * Y_N + dc * 21600;
  for (int s = t; s < 5400; s += 256) {
    float4 v = *(const float4*)&pb[4 * s];
#pragma unroll
    for (int c = 1; c < NCHUNK; ++c) {
      float4 w = *(const float4*)&pb[(size_t)c * Y_TOT + 4 * s];
      v.x += w.x; v.y += w.y; v.z += w.z; v.w += w.w;
    }
    *(float4*)&buf[4 * s] = v;
  }
  __syncthreads();
  if (t < 200) {
    int wc = t % 10, hc = (t / 10) % 10, p = t / 100;
    float m = -3.4e38f;
    for (int od = 0; od < 6; ++od)
      for (int j = 0; j < 6; ++j)
#pragma unroll
        for (int k = 0; k < 3; ++k)
          m = fmaxf(m, buf[(od * 60 + 6 * hc + j) * 60 + 6 * wc + 3 * p + k]);
    red[t] = m;
  }
  __syncthreads();
  if (t < 100) out[blk * 100 + t] = fmaxf(red[t], red[t + 100]) + ws[woff + 4096];
}

// ---------------- prep: weight oc-sum + bias sum -----------------------
__global__ __launch_bounds__(128) void prep2(const float* __restrict__ w,
                                             const float* __restrict__ bias,
                                             float* __restrict__ ws, int woff) {
  int i = blockIdx.x, t = threadIdx.x;
  if (t < 125) {
    const float* wp = w + (size_t)i * 64 * 125 + t;
    float v = 0.f;
#pragma unroll 8
    for (int o = 0; o < 64; ++o) v += wp[o * 125];
    ws[woff + i * 128 + t] = v;
  }
  if (i == 0 && t == 126) {
    float b = 0.f;
    for (int o = 0; o < 64; ++o) b += bias[o];
    ws[woff + 4096] = b;
  }
}

// ================= fallback (round-1 kernels, need only ~64 KB ws) ======
__global__ __launch_bounds__(256) void prep_kernel(const float* __restrict__ w,
                                                   const float* __restrict__ bias,
                                                   float* __restrict__ ws) {
  int i = blockIdx.x;
  int t = threadIdx.x;
  for (int s = t; s < 512; s += 256) {
    int kw = s & 7, kh = (s >> 3) & 7, kd = s >> 6;
    float v = 0.f;
    if (kd < 5 && kh < 5 && kw < 5) {
      const float* wp = w + (size_t)i * 64 * 125 + kd * 25 + kh * 5 + kw;
#pragma unroll 8
      for (int o = 0; o < 64; ++o) v += wp[o * 125];
    }
    ws[i * 512 + s] = v;
  }
  if (i == 0 && t == 0) {
    float b = 0.f;
    for (int o = 0; o < 64; ++o) b += bias[o];
    ws[16384] = b;
  }
}

__global__ __launch_bounds__(192) void conv_pool_kernel(const float* __restrict__ x,
                                                        const float* __restrict__ ws,
                                                        float* __restrict__ out) {
  __shared__ __align__(16) float xs[4080];
  __shared__ __align__(16) float wl[3200];
  __shared__ float red[360];
  int b = blockIdx.x;
  int wc2 = b % 5, hq = (b / 5) % 2, dc = (b / 10) % 5, n = b / 50;
  int t = threadIdx.x;
  int td = t / 30, ohl = t % 30;
  int a0 = (td + 1) >> 1, b0 = (ohl + 1) >> 1;
  const float* xn = x + (size_t)n * NSTRIDE;
  int id_base = 3 * dc - 1, ih_base = 15 * hq - 1, iw_base = 6 * wc2 - 1;
  float acc0=0,acc1=0,acc2=0,acc3=0,acc4=0,acc5=0,acc6=0,acc7=0,acc8=0,acc9=0,acc10=0,acc11=0;
  for (int p = 0; p < 8; ++p) {
    for (int s = t; s < 2720; s += 192) {
      int c = s & 7; int r = s >> 3; int bh = r % 17; int r2 = r / 17;
      int ad = r2 % 5; int ic = r2 / 5;
      int id = id_base + ad, ih = ih_base + bh, iw = iw_base + c;
      float v = 0.f;
      if ((id | ih | iw) >= 0)
        v = xn[(size_t)(p * 4 + ic) * CHSTR + id * (HIN * WIN) + ih * WIN + iw];
      xs[(ic * 5 + ad) * 204 + bh * 12 + c] = v;
    }
    for (int s = t; s < 2048; s += 192) {
      int kw = s & 7, kh = (s >> 3) & 7, kd = (s >> 6) & 7, ic = s >> 9;
      wl[ic * 800 + kd * 100 + kh * 12 + kw] = ws[(p * 4 + ic) * 512 + (s & 511)];
    }
    __syncthreads();
    if (t < 180) {
      for (int ic = 0; ic < 4; ++ic) {
        const float* xc = &xs[ic * 1020];
        const float* wcc = &wl[ic * 800];
#pragma unroll
        for (int jd = 0; jd < 3; ++jd) {
          int ad = a0 + jd;
          int kd = (td + 4 - 2 * ad) & 7;
          if (ad > 4) ad = 4;
#pragma unroll
          for (int jh = 0; jh < 3; ++jh) {
            int bh = b0 + jh;
            int kh = (ohl + 4 - 2 * bh) & 7;
            if (bh > 16) bh = 16;
            const float* xr = xc + ad * 204 + bh * 12;
            const float* wr = wcc + kd * 100 + kh * 12;
            float4 xlo = *(const float4*)(xr);
            float4 xhi = *(const float4*)(xr + 4);
            float4 wv = *(const float4*)(wr);
            float w4 = wr[4];
            float x0=xlo.x,x1=xlo.y,x2=xlo.z,x3=xlo.w,x4=xhi.x,x5=xhi.y,x6=xhi.z,x7=xhi.w;
            float w0=wv.x,w1=wv.y,w2=wv.z,w3=wv.w;
            acc0+=x0*w4; acc0+=x1*w2; acc0+=x2*w0; acc1+=x1*w3; acc1+=x2*w1;
            acc2+=x1*w4; acc2+=x2*w2; acc2+=x3*w0; acc3+=x2*w3; acc3+=x3*w1;
            acc4+=x2*w4; acc4+=x3*w2; acc4+=x4*w0; acc5+=x3*w3; acc5+=x4*w1;
            acc6+=x3*w4; acc6+=x4*w2; acc6+=x5*w0; acc7+=x4*w3; acc7+=x5*w1;
            acc8+=x4*w4; acc8+=x5*w2; acc8+=x6*w0; acc9+=x5*w3; acc9+=x6*w1;
            acc10+=x5*w4; acc10+=x6*w2; acc10+=x7*w0; acc11+=x6*w3; acc11+=x7*w1;
          }
        }
      }
    }
    __syncthreads();
  }
  if (t < 180) {
    float g0 = fmaxf(fmaxf(fmaxf(acc0,acc1),fmaxf(acc2,acc3)),fmaxf(acc4,acc5));
    float g1 = fmaxf(fmaxf(fmaxf(acc6,acc7),fmaxf(acc8,acc9)),fmaxf(acc10,acc11));
    red[t * 2] = g0; red[t * 2 + 1] = g1;
  }
  __syncthreads();
  if (t < 10) {
    int hs = t >> 1, wsub = t & 1;
    float m = -3.4e38f;
    for (int tdd = 0; tdd < 6; ++tdd)
      for (int j = 0; j < 6; ++j) m = fmaxf(m, red[(tdd * 30 + hs * 6 + j) * 2 + wsub]);
    m += ws[16384];
    out[((n * 5 + dc) * 10 + (5 * hq + hs)) * 10 + (2 * wc2 + wsub)] = m;
  }
}

// ---------------- launch ----------------------------------------------
extern "C" void kernel_launch(void* const* d_in, const int* in_sizes, int n_in,
                              void* d_out, int out_size, void* d_ws, size_t ws_size,
                              hipStream_t stream) {
  const float* x    = (const float*)d_in[0];
  const float* w    = (const float*)d_in[1];
  const float* bias = (const float*)d_in[2];
  float* outp = (float*)d_out;
  float* ws   = (float*)d_ws;

  const size_t need4 = ((size_t)4 * Y_TOT + 4097) * 4;
  const size_t need2 = ((size_t)2 * Y_TOT + 4097) * 4;
  const size_t need1 = ((size_t)1 * Y_TOT + 4097) * 4;

  if (ws_size >= need4) {
    int woff = 4 * Y_TOT;
    prep2<<<32, 128, 0, stream>>>(w, bias, ws, woff);
    conv_stage1<4><<<320 * 4, 256, 0, stream>>>(x, ws, ws, woff);
    pool_stage2<4><<<80, 256, 0, stream>>>(ws, ws, outp, woff);
  } else if (ws_size >= need2) {
    int woff = 2 * Y_TOT;
    prep2<<<32, 128, 0, stream>>>(w, bias, ws, woff);
    conv_stage1<2><<<320 * 2, 256, 0, stream>>>(x, ws, ws, woff);
    pool_stage2<2><<<80, 256, 0, stream>>>(ws, ws, outp, woff);
  } else if (ws_size >= need1) {
    int woff = 1 * Y_TOT;
    prep2<<<32, 128, 0, stream>>>(w, bias, ws, woff);
    conv_stage1<1><<<320 * 1, 256, 0, stream>>>(x, ws, ws, woff);
    pool_stage2<1><<<80, 256, 0, stream>>>(ws, ws, outp, woff);
  } else {
    prep_kernel<<<32, 256, 0, stream>>>(w, bias, ws);
    conv_pool_kernel<<<800, 192, 0, stream>>>(x, ws, outp);
  }
}